// Round 1
// baseline (1097.083 us; speedup 1.0000x reference)
//
#include <hip/hip_runtime.h>
#include <math.h>

#define NMOL 512
#define NATOM 64
#define NFLAT (NMOL*NATOM)
#define AEVL 384
#define XW 36            // extra feature sideband width: 32 qraev + q + esp + 2 pad
#define D0 256
#define D1 192
#define D2 160
#define MPAD 33024       // max padded compact rows (32768 + 4*63 rounded up)

__constant__ float c_sigma[8] = {0.5515909f,1.8886297f,1.3225029f,1.2316629f,
                                 2.1884933f,1.7750372f,1.3677907f,1.3820058f};

__device__ __forceinline__ float wsum(float v){
  #pragma unroll
  for (int o=1;o<64;o<<=1) v += __shfl_xor(v,o);
  return v;
}

// ---------------- init: zero extra sideband + meta counters ----------------
__global__ void init_kernel(float* __restrict__ extra, int* __restrict__ meta, int n){
  int g = blockIdx.x*256 + threadIdx.x;
  if (g < n) extra[g] = 0.f;
  if (g < 18) meta[g] = 0;
}

// ---------------- distances + per-atom species data ----------------
__global__ void prep_kernel(const int* __restrict__ species,
                            const float* __restrict__ coord,
                            float* __restrict__ dbuf, float* __restrict__ sig,
                            float* __restrict__ invj, float* __restrict__ pmf){
  int m = blockIdx.x, t = threadIdx.x;
  __shared__ float c[192];
  if (t < 192) c[t] = coord[m*192 + t];
  __syncthreads();
  #pragma unroll
  for (int k=0;k<16;k++){
    int p = t + 256*k;
    int i = p >> 6, j = p & 63;
    float dx=c[i*3]-c[j*3], dy=c[i*3+1]-c[j*3+1], dz=c[i*3+2]-c[j*3+2];
    dbuf[m*4096 + p] = sqrtf(dx*dx+dy*dy+dz*dz + 1e-16f) / 0.529177249f;
  }
  if (t < 64){
    int s = species[m*64+t];
    float sg = c_sigma[s < 0 ? 7 : s];
    sig[m*64+t]  = sg;
    invj[m*64+t] = 1.7724539f * sg;   // sqrt(pi) fp32
    pmf[m*64+t]  = (s>=0) ? 1.f : 0.f;
  }
}

// ---------------- species bucketing ----------------
__global__ void count_kernel(const int* __restrict__ species, int* __restrict__ meta){
  int g = blockIdx.x*256 + threadIdx.x;
  int s = species[g];
  if (s >= 0) atomicAdd(&meta[s], 1);
}
__global__ void plan_kernel(int* __restrict__ meta){
  // meta: [0..3] counts, [4..8] base(64-aligned), [9..13] tile_base, [14..17] scatter ctr
  int b=0, tb=0;
  meta[4]=0; meta[9]=0;
  for (int s=0;s<4;s++){
    int tiles = (meta[s]+63)>>6;
    b  += tiles<<6;  tb += tiles;
    meta[5+s]  = b;  meta[10+s] = tb;
  }
}
__global__ void scatter_kernel(const int* __restrict__ species, int* __restrict__ meta,
                               int* __restrict__ idxarr){
  int g = blockIdx.x*256 + threadIdx.x;
  int s = species[g];
  if (s >= 0){
    int pos = atomicAdd(&meta[14+s], 1);
    idxarr[meta[4+s] + pos] = g;
  }
}

// ---------------- fp32 tiled GEMM: C[row][n] = act(A[row][:] @ W[s] + b[s]) ----------------
// 64x64 tile, 256 threads, 4x4 microtile. L0M: A = [aev | extra] gathered via idxarr.
template<int L0M>
__launch_bounds__(256)
__global__ void gemm_kernel(const float* __restrict__ Ain,
                            const float* __restrict__ aev,
                            const float* __restrict__ extra,
                            const int* __restrict__ idxarr,
                            const int* __restrict__ meta,
                            const float* __restrict__ Wall,   // [4][K][N]
                            const float* __restrict__ Ball,   // [4][N]
                            float* __restrict__ C,
                            int K, int N, int act){
  int t = blockIdx.x;
  if (t >= meta[13]) return;
  int s = 0;
  while (s < 3 && t >= meta[10+s]) s++;
  int trow = t - meta[9+s];
  int row0 = meta[4+s] + (trow<<6);
  int mrem = meta[s] - (trow<<6); if (mrem > 64) mrem = 64;
  int n0 = blockIdx.y << 6;
  const float* W = Wall + (size_t)s*K*N;

  __shared__ __align__(16) float As[16][64];
  __shared__ __align__(16) float Bs[16][64];
  int tid = threadIdx.x;
  int lr  = tid>>2,  kq = (tid&3)<<2;   // A load: row, k-quad
  int bkk = tid>>4,  bn = (tid&15)<<2;  // B load: k-row, col-quad
  int ty  = tid>>4,  tx = tid&15;       // compute mapping

  bool avalid = lr < mrem;
  int atom = 0;
  const float* arowp = nullptr;
  if (L0M) { if (avalid) atom = idxarr[row0+lr]; }
  else     { arowp = Ain + (size_t)(row0+lr)*K; }

  float acc[4][4] = {{0.f,0.f,0.f,0.f},{0.f,0.f,0.f,0.f},{0.f,0.f,0.f,0.f},{0.f,0.f,0.f,0.f}};
  int nk = (K+15)>>4;
  for (int kt=0; kt<nk; ++kt){
    int k0 = kt<<4;
    float4 av = make_float4(0.f,0.f,0.f,0.f);
    if (avalid){
      if (L0M){
        if (k0 < AEVL) av = *reinterpret_cast<const float4*>(aev   + (size_t)atom*AEVL + k0 + kq);
        else           av = *reinterpret_cast<const float4*>(extra + (size_t)atom*XW + (k0-AEVL) + kq);
      } else {
        av = *reinterpret_cast<const float4*>(arowp + k0 + kq);
      }
    }
    float4 bv = make_float4(0.f,0.f,0.f,0.f);
    int kB = k0 + bkk;
    if (kB < K){
      int cb = n0 + bn;
      const float* wr = W + (size_t)kB*N;
      if (cb + 3 < N) bv = *reinterpret_cast<const float4*>(wr + cb);
      else if (cb < N){
        bv.x = wr[cb];
        if (cb+1 < N) bv.y = wr[cb+1];
        if (cb+2 < N) bv.z = wr[cb+2];
      }
    }
    __syncthreads();
    As[kq  ][lr] = av.x;
    As[kq+1][lr] = av.y;
    As[kq+2][lr] = av.z;
    As[kq+3][lr] = av.w;
    *reinterpret_cast<float4*>(&Bs[bkk][bn]) = bv;
    __syncthreads();
    #pragma unroll
    for (int kk=0;kk<16;kk++){
      float4 a4 = *reinterpret_cast<const float4*>(&As[kk][ty<<2]);
      float4 b4 = *reinterpret_cast<const float4*>(&Bs[kk][tx<<2]);
      float aa[4] = {a4.x,a4.y,a4.z,a4.w};
      float bb[4] = {b4.x,b4.y,b4.z,b4.w};
      #pragma unroll
      for (int i=0;i<4;i++)
        #pragma unroll
        for (int j=0;j<4;j++)
          acc[i][j] += aa[i]*bb[j];
    }
  }
  const float* bias = Ball + s*N;
  #pragma unroll
  for (int i=0;i<4;i++){
    int lrow = (ty<<2) + i;
    if (lrow >= mrem) continue;
    size_t rb = (size_t)(row0+lrow)*N;
    #pragma unroll
    for (int j=0;j<4;j++){
      int col = n0 + (tx<<2) + j;
      if (col >= N) continue;
      float v = acc[i][j] + bias[col];
      if (act) v = v > 0.f ? v : 0.1f*expm1f(v*10.f);
      C[rb + col] = v;
    }
  }
}

// ---------------- output layer: 160 -> 1 dot per row, scatter to atom ----------------
__global__ void layer3_kernel(const float* __restrict__ h2,
                              const int* __restrict__ idxarr,
                              const int* __restrict__ meta,
                              const float* __restrict__ W3,  // [4][160]
                              const float* __restrict__ b3,  // [4]
                              float* __restrict__ outv){
  int row = blockIdx.x*4 + (threadIdx.x>>6);
  int lane = threadIdx.x & 63;
  if (row >= meta[8]) return;
  int s = 0;
  while (s < 3 && row >= meta[5+s]) s++;
  int lrow = row - meta[4+s];
  if (lrow >= meta[s]) return;
  const float* h = h2 + (size_t)row*D2;
  const float* w = W3 + s*D2;
  float v = h[lane]*w[lane] + h[lane+64]*w[lane+64];
  if (lane < 32) v += h[lane+128]*w[lane+128];
  v = wsum(v);
  if (lane == 0) outv[idxarr[row]] = v + b3[s];
}

// ---------------- charge update ----------------
__global__ void qupdate_kernel(const float* __restrict__ chi, const float* __restrict__ invj,
                               const float* __restrict__ pmf, const float* __restrict__ netq,
                               float* __restrict__ q, float* __restrict__ extra){
  int m = blockIdx.x, a = threadIdx.x, g = m*64+a;
  float pm = pmf[g], ij = invj[g];
  float c = pm > 0.f ? chi[g] : 0.f;
  float num = wsum(c*ij);
  float den = wsum(ij*pm);
  float corr = (netq[m] + num) / den;
  float qa = -ij*(c - corr)*pm;
  q[g] = qa;
  extra[(size_t)g*XW + 32] = qa;
}

// ---------------- ESP via erf ----------------
__global__ void esp_kernel(const float* __restrict__ dbuf, const float* __restrict__ q,
                           const float* __restrict__ sig, const float* __restrict__ pmf,
                           float* __restrict__ extra){
  int m = blockIdx.x, i = threadIdx.x, g = m*64+i;
  __shared__ float qs[64], sg[64], pms[64];
  qs[i]=q[g]; sg[i]=sig[g]; pms[i]=pmf[g];
  __syncthreads();
  float si2 = sg[i]*sg[i];
  float acc = 0.f;
  const float* dr = dbuf + (size_t)m*4096;
  for (int j=0;j<64;j++){
    if (j==i) continue;
    float d = dr[j*64 + i];
    float ss = fmaxf(si2 + sg[j]*sg[j], 1e-8f);
    acc += qs[j]*pms[j]*erff(d/sqrtf(2.f*ss))/d;
  }
  extra[(size_t)g*XW + 33] = acc * pms[i];
}

// ---------------- radial qaev ----------------
__global__ void qraev_kernel(const float* __restrict__ dbuf, const float* __restrict__ q,
                             const float* __restrict__ pmf, float* __restrict__ extra){
  int m = blockIdx.x;
  int i = threadIdx.x & 63, rg = threadIdx.x >> 6;
  __shared__ float qs[64], pms[64];
  if (threadIdx.x < 64){ qs[i]=q[m*64+i]; pms[i]=pmf[m*64+i]; }
  __syncthreads();
  float pmi = pms[i];
  float acc[8] = {0.f,0.f,0.f,0.f,0.f,0.f,0.f,0.f};
  const float* dr = dbuf + (size_t)m*4096;
  const float step = 8.2f/31.f;
  float rbase = 0.8f + (rg*8)*step;
  for (int j=0;j<64;j++){
    if (j==i) continue;
    float d = dr[j*64+i];
    float w = 0.f;
    if (d < 10.f) w = 0.25f*(0.5f*cosf(0.31415926535f*d)+0.5f)*qs[j]*pms[j]*pmi;
    if (w != 0.f){
      #pragma unroll
      for (int r=0;r<8;r++){
        float dd = d - (rbase + r*step);
        acc[r] += w*expf(-4.f*dd*dd);
      }
    }
  }
  float* xr = extra + (size_t)(m*64+i)*XW + rg*8;
  #pragma unroll
  for (int r=0;r<8;r++) xr[r] = acc[r];
}

// ---------------- screened Coulomb + energy + outputs ----------------
__global__ void final_kernel(const float* __restrict__ dbuf, const float* __restrict__ q,
                             const float* __restrict__ pmf, const float* __restrict__ ae,
                             const int* __restrict__ species, float* __restrict__ out){
  int m = blockIdx.x, a = threadIdx.x, g = m*64+a;
  __shared__ float qs[64], pms[64];
  qs[a]=q[g]; pms[a]=pmf[g];
  __syncthreads();
  float acc=0.f;
  const float* dr = dbuf + (size_t)m*4096;
  for (int b=0;b<64;b++){
    if (b==a) continue;
    float d = dr[b*64+a];
    float sgm = 1.f/(1.f+expf(-(d-2.2f)*8.5f));
    acc += qs[b]*pms[b]*sgm/d;
  }
  float e = 0.5f*qs[a]*pms[a]*acc;          // triu(k=1) sum of symmetric matrix
  float aea = pms[a]>0.f ? ae[g] : 0.f;
  float tot = wsum(e + aea);
  if (a == 0) out[NFLAT + m] = tot;
  out[g] = (float)species[g];
  out[NFLAT + NMOL + g] = qs[a];
}

extern "C" void kernel_launch(void* const* d_in, const int* in_sizes, int n_in,
                              void* d_out, int out_size, void* d_ws, size_t ws_size,
                              hipStream_t stream){
  const int*   species = (const int*)d_in[0];
  const float* coord   = (const float*)d_in[1];
  const float* netq    = (const float*)d_in[2];
  const float* aev     = (const float*)d_in[3];
  const float* cW[4] = {(const float*)d_in[4],(const float*)d_in[6],(const float*)d_in[8],(const float*)d_in[10]};
  const float* cB[4] = {(const float*)d_in[5],(const float*)d_in[7],(const float*)d_in[9],(const float*)d_in[11]};
  const float* aW[4] = {(const float*)d_in[12],(const float*)d_in[14],(const float*)d_in[16],(const float*)d_in[18]};
  const float* aB[4] = {(const float*)d_in[13],(const float*)d_in[15],(const float*)d_in[17],(const float*)d_in[19]};

  // workspace layout (floats): ~73 MB total
  float* f = (float*)d_ws;
  size_t o = 0;
  float* dbuf  = f + o; o += (size_t)NMOL*4096;
  float* sig   = f + o; o += NFLAT;
  float* invj  = f + o; o += NFLAT;
  float* pmf   = f + o; o += NFLAT;
  float* q     = f + o; o += NFLAT;
  float* chi   = f + o; o += NFLAT;
  float* extra = f + o; o += (size_t)NFLAT*XW + 64;
  float* h0    = f + o; o += (size_t)MPAD*D0;
  float* h1    = f + o; o += (size_t)MPAD*D1;
  float* h2    = h0;   // L2 reads h1 only -> alias h0
  int* meta    = (int*)(f + o); o += 64;
  int* idxarr  = (int*)(f + o); o += MPAD;

  int xels = NFLAT*XW + 64;
  init_kernel<<<dim3((xels+255)/256), 256, 0, stream>>>(extra, meta, xels);
  prep_kernel<<<dim3(NMOL), 256, 0, stream>>>(species, coord, dbuf, sig, invj, pmf);
  count_kernel<<<dim3(NFLAT/256), 256, 0, stream>>>(species, meta);
  plan_kernel<<<dim3(1), 1, 0, stream>>>(meta);
  scatter_kernel<<<dim3(NFLAT/256), 256, 0, stream>>>(species, meta, idxarr);

  for (int pass=0; pass<3; ++pass){
    const float* const* Wp = (pass<2) ? cW : aW;
    const float* const* Bp = (pass<2) ? cB : aB;
    gemm_kernel<1><<<dim3(516,4), 256, 0, stream>>>(nullptr, aev, extra, idxarr, meta,
                                                    Wp[0], Bp[0], h0, 418, D0, 1);
    gemm_kernel<0><<<dim3(516,3), 256, 0, stream>>>(h0, aev, extra, idxarr, meta,
                                                    Wp[1], Bp[1], h1, D0, D1, 1);
    gemm_kernel<0><<<dim3(516,3), 256, 0, stream>>>(h1, aev, extra, idxarr, meta,
                                                    Wp[2], Bp[2], h2, D1, D2, 1);
    layer3_kernel<<<dim3(MPAD/4), 256, 0, stream>>>(h2, idxarr, meta, Wp[3], Bp[3], chi);
    if (pass < 2){
      qupdate_kernel<<<dim3(NMOL), 64, 0, stream>>>(chi, invj, pmf, netq, q, extra);
      esp_kernel<<<dim3(NMOL), 64, 0, stream>>>(dbuf, q, sig, pmf, extra);
      qraev_kernel<<<dim3(NMOL), 256, 0, stream>>>(dbuf, q, pmf, extra);
    }
  }
  final_kernel<<<dim3(NMOL), 64, 0, stream>>>(dbuf, q, pmf, chi, species, (float*)d_out);
}

// Round 5
// 508.865 us; speedup vs baseline: 2.1559x; 2.1559x over previous
//
#include <hip/hip_runtime.h>
#include <math.h>

#define NMOL 512
#define NATOM 64
#define NFLAT (NMOL*NATOM)
#define AEVL 384
#define XW 36            // extra feature sideband: 32 qraev + q + esp + 2 pad
#define D0 256
#define D1 192
#define D2 160
#define MPAD 33024       // max padded compact rows

typedef _Float16 h8 __attribute__((ext_vector_type(8)));
typedef _Float16 h4 __attribute__((ext_vector_type(4)));
typedef float    f4 __attribute__((ext_vector_type(4)));

__constant__ float c_sigma[8] = {0.5515909f,1.8886297f,1.3225029f,1.2316629f,
                                 2.1884933f,1.7750372f,1.3677907f,1.3820058f};

__device__ __forceinline__ float wsum(float v){
  #pragma unroll
  for (int o=1;o<64;o<<=1) v += __shfl_xor(v,o);
  return v;
}

// ---------------- distances + per-atom species data + per-molecule histogram ----------------
__global__ void prep_kernel(const int* __restrict__ species,
                            const float* __restrict__ coord,
                            float* __restrict__ dbuf, float* __restrict__ sig,
                            float* __restrict__ invj, float* __restrict__ pmf,
                            int* __restrict__ blkhist, float* __restrict__ extra){
  int m = blockIdx.x, t = threadIdx.x;
  __shared__ float c[192];
  if (t < 192) c[t] = coord[m*192 + t];
  __syncthreads();
  #pragma unroll
  for (int k=0;k<16;k++){
    int p = t + 256*k;
    int i = p >> 6, j = p & 63;
    float dx=c[i*3]-c[j*3], dy=c[i*3+1]-c[j*3+1], dz=c[i*3+2]-c[j*3+2];
    dbuf[m*4096 + p] = sqrtf(dx*dx+dy*dy+dz*dz + 1e-16f) / 0.529177249f;
  }
  if (t < 64){   // wave 0 exactly
    int g = m*64+t;
    int s = species[g];
    float sg = c_sigma[s < 0 ? 7 : s];
    sig[g]  = sg;
    invj[g] = 1.7724539f * sg;   // sqrt(pi) fp32
    pmf[g]  = (s>=0) ? 1.f : 0.f;
    extra[(size_t)g*XW + 34] = 0.f;   // zero the pad lanes (ws is poisoned)
    extra[(size_t)g*XW + 35] = 0.f;
    #pragma unroll
    for (int sp=0;sp<4;sp++){
      unsigned long long mask = __ballot(s==sp);
      if (t==0) blkhist[m*4+sp] = __popcll(mask);
    }
  }
}

// ---------------- plan: totals, 64-aligned bases, tile bases, per-molecule offsets ----------------
// meta: [0..3] counts, [4..8] base(64-aligned, [8]=total rows), [9..13] tile_base ([13]=total tiles)
__global__ void plan_kernel(const int* __restrict__ blkhist, int* __restrict__ meta,
                            int* __restrict__ blkoff){
  __shared__ int tot[4], base[4];
  int t = threadIdx.x;
  if (t < 4){
    int sum = 0;
    for (int m=0;m<NMOL;m++) sum += blkhist[m*4+t];
    tot[t] = sum;
  }
  __syncthreads();
  if (t == 0){
    int b=0, tb=0;
    meta[4]=0; meta[9]=0;
    for (int s=0;s<4;s++){
      meta[s] = tot[s];
      base[s] = b;
      int tiles = (tot[s]+63)>>6;
      b  += tiles<<6;  tb += tiles;
      meta[5+s]  = b;  meta[10+s] = tb;
    }
  }
  __syncthreads();
  if (t < 4){
    int run = base[t];
    for (int m=0;m<NMOL;m++){ blkoff[m*4+t] = run; run += blkhist[m*4+t]; }
  }
}

// ---------------- deterministic atomic-free scatter: one wave per molecule ----------------
__global__ void scatter_kernel(const int* __restrict__ species,
                               const int* __restrict__ blkoff,
                               int* __restrict__ idxarr){
  int m = blockIdx.x, a = threadIdx.x, g = m*64+a;
  int s = species[g];
  unsigned long long below = (1ull<<a) - 1ull;
  #pragma unroll
  for (int sp=0;sp<4;sp++){
    unsigned long long mask = __ballot(s==sp);
    if (s==sp){
      int rank = __popcll(mask & below);
      idxarr[blkoff[m*4+sp] + rank] = g;
    }
  }
}

// ---------------- fp16 MFMA tiled GEMM: C[row][n] = act(A[row][:] @ W[s] + b[s]) ----------------
// 64x64 tile, 4 waves; wave w computes rows [w*16,w*16+16) x 64 cols via 16x16x32 MFMA.
// A,B staged in LDS as fp16 with identical k-decomposition (layout-permutation safe).
// L0M: 0 = plain A; 1 = gather [aev|extra] via idxarr; 2 = gather aev only (pass 0)
template<int L0M>
__launch_bounds__(256)
__global__ void gemm_mfma(const float* __restrict__ Ain,
                          const float* __restrict__ aev,
                          const float* __restrict__ extra,
                          const int* __restrict__ idxarr,
                          const int* __restrict__ meta,
                          const float* __restrict__ Wall,   // [4][K][N]
                          const float* __restrict__ Ball,   // [4][N]
                          float* __restrict__ C,
                          int K, int N, int act){
  int t = blockIdx.x;
  if (t >= meta[13]) return;
  int s = 0;
  while (s < 3 && t >= meta[10+s]) s++;
  int trow = t - meta[9+s];
  int row0 = meta[4+s] + (trow<<6);
  int mrem = meta[s] - (trow<<6); if (mrem > 64) mrem = 64;
  int n0 = blockIdx.y << 6;
  const float* W = Wall + (size_t)s*K*N;

  __shared__ _Float16 As[64][40];   // [row][k], stride 80B -> 2-way bank aliasing (free)
  __shared__ _Float16 Bs[64][40];   // [col][k] (transposed W tile)

  int tid = threadIdx.x;
  int lr = tid>>2, kq = (tid&3)<<3;     // A staging: row, k-octet
  int bn = tid&63, bk = (tid>>6)<<2;    // B staging: col, k-quad (and +16)
  int w  = tid>>6, l = tid&63;          // compute: wave, lane
  int lr16 = l&15, lg = l>>4;

  bool avalid = lr < mrem;
  const float* arow = nullptr;
  const float* aerow = nullptr;
  const float* exrow = nullptr;
  if (L0M >= 1){
    if (avalid){
      int atom = idxarr[row0+lr];
      aerow = aev   + (size_t)atom*AEVL;
      exrow = extra + (size_t)atom*XW;
    }
  } else {
    arow = Ain + (size_t)(row0+lr)*K;
  }

  f4 zero4; zero4[0]=0.f; zero4[1]=0.f; zero4[2]=0.f; zero4[3]=0.f;
  f4 acc[4] = {zero4, zero4, zero4, zero4};

  int KA = (L0M==2) ? AEVL : K;
  int KT = (KA+31)>>5;
  int cb = n0 + bn;
  for (int kt=0; kt<KT; ++kt){
    int k0 = kt<<5;
    // ---- global loads to regs ----
    f4 u; u[0]=0.f;u[1]=0.f;u[2]=0.f;u[3]=0.f;
    f4 v = u;
    if (avalid){
      int ka = k0 + kq;
      const float* src;
      if (L0M >= 1) src = (ka < AEVL) ? (aerow + ka) : (exrow + (ka - AEVL));
      else          src = arow + ka;
      u = *reinterpret_cast<const f4*>(src);
      v = *reinterpret_cast<const f4*>(src+4);
    }
    float b0=0.f,b1=0.f,b2=0.f,b3=0.f,b4=0.f,b5=0.f,b6=0.f,b7=0.f;
    if (cb < N){
      int ka = k0 + bk;
      const float* wp = W + (size_t)ka*N + cb;
      if (ka   < K) b0 = wp[0];
      if (ka+1 < K) b1 = wp[(size_t)N];
      if (ka+2 < K) b2 = wp[(size_t)2*N];
      if (ka+3 < K) b3 = wp[(size_t)3*N];
      if (ka+16 < K) b4 = wp[(size_t)16*N];
      if (ka+17 < K) b5 = wp[(size_t)17*N];
      if (ka+18 < K) b6 = wp[(size_t)18*N];
      if (ka+19 < K) b7 = wp[(size_t)19*N];
    }
    __syncthreads();
    // ---- LDS writes (fp16) ----
    h8 ah;
    ah[0]=(_Float16)u[0]; ah[1]=(_Float16)u[1]; ah[2]=(_Float16)u[2]; ah[3]=(_Float16)u[3];
    ah[4]=(_Float16)v[0]; ah[5]=(_Float16)v[1]; ah[6]=(_Float16)v[2]; ah[7]=(_Float16)v[3];
    *reinterpret_cast<h8*>(&As[lr][kq]) = ah;
    h4 bl, bh;
    bl[0]=(_Float16)b0; bl[1]=(_Float16)b1; bl[2]=(_Float16)b2; bl[3]=(_Float16)b3;
    bh[0]=(_Float16)b4; bh[1]=(_Float16)b5; bh[2]=(_Float16)b6; bh[3]=(_Float16)b7;
    *reinterpret_cast<h4*>(&Bs[bn][bk])    = bl;
    *reinterpret_cast<h4*>(&Bs[bn][bk+16]) = bh;
    __syncthreads();
    // ---- MFMA ----
    h8 af = *reinterpret_cast<const h8*>(&As[w*16 + lr16][lg*8]);
    #pragma unroll
    for (int c=0;c<4;c++){
      h8 bf = *reinterpret_cast<const h8*>(&Bs[c*16 + lr16][lg*8]);
      acc[c] = __builtin_amdgcn_mfma_f32_16x16x32_f16(af, bf, acc[c], 0, 0, 0);
    }
  }
  // ---- epilogue: C/D layout col=lane&15, row=(lane>>4)*4+reg (HW-verified) ----
  const float* bias = Ball + s*N;
  #pragma unroll
  for (int c=0;c<4;c++){
    int col = n0 + c*16 + lr16;
    if (col >= N) continue;
    float bs = bias[col];
    #pragma unroll
    for (int r=0;r<4;r++){
      int lrow = w*16 + lg*4 + r;
      if (lrow >= mrem) continue;
      float vv = acc[c][r] + bs;
      if (act) vv = vv > 0.f ? vv : 0.1f*expm1f(vv*10.f);
      C[(size_t)(row0+lrow)*N + col] = vv;
    }
  }
}

// ---------------- output layer: 160 -> 1 dot per row, scatter to atom ----------------
__global__ void layer3_kernel(const float* __restrict__ h2,
                              const int* __restrict__ idxarr,
                              const int* __restrict__ meta,
                              const float* __restrict__ W3,  // [4][160]
                              const float* __restrict__ b3,  // [4]
                              float* __restrict__ outv){
  int row = blockIdx.x*4 + (threadIdx.x>>6);
  int lane = threadIdx.x & 63;
  if (row >= meta[8]) return;
  int s = 0;
  while (s < 3 && row >= meta[5+s]) s++;
  int lrow = row - meta[4+s];
  if (lrow >= meta[s]) return;
  const float* h = h2 + (size_t)row*D2;
  const float* w = W3 + s*D2;
  float v = h[lane]*w[lane] + h[lane+64]*w[lane+64];
  if (lane < 32) v += h[lane+128]*w[lane+128];
  v = wsum(v);
  if (lane == 0) outv[idxarr[row]] = v + b3[s];
}

// ---------------- fused charge iteration: qupdate + esp + qraev ----------------
__global__ void iter_kernel(const float* __restrict__ chi, const float* __restrict__ invj,
                            const float* __restrict__ pmf, const float* __restrict__ netq,
                            const float* __restrict__ dbuf, const float* __restrict__ sig,
                            float* __restrict__ q, float* __restrict__ extra){
  int m = blockIdx.x, tid = threadIdx.x;
  int i = tid & 63, w = tid >> 6;
  __shared__ float qs[64], pms[64], sg2[64];
  __shared__ float esp4[4][64];
  if (tid < 64){
    int g = m*64 + i;
    float pm = pmf[g], ij = invj[g];
    float c = pm > 0.f ? chi[g] : 0.f;
    float num = wsum(c*ij);
    float den = wsum(ij*pm);
    float corr = (netq[m] + num) / den;
    float qa = -ij*(c - corr)*pm;
    q[g] = qa;
    extra[(size_t)g*XW + 32] = qa;
    qs[i] = qa; pms[i] = pm;
    float s0 = sig[g]; sg2[i] = s0*s0;
  }
  __syncthreads();
  const float* dr = dbuf + (size_t)m*4096;
  // esp: each wave handles 16 j's per atom
  {
    float si2 = sg2[i];
    float acc = 0.f;
    for (int jj=0;jj<16;jj++){
      int j = w*16 + jj;
      if (j==i) continue;
      float d = dr[j*64 + i];
      float ss = fmaxf(si2 + sg2[j], 1e-8f);
      acc += qs[j]*pms[j]*erff(d/sqrtf(2.f*ss))/d;
    }
    esp4[w][i] = acc;
  }
  __syncthreads();
  if (tid < 64){
    int g = m*64+i;
    extra[(size_t)g*XW + 33] = (esp4[0][i]+esp4[1][i]+esp4[2][i]+esp4[3][i]) * pms[i];
  }
  // qraev: wave w handles r-bins [w*8, w*8+8)
  float pmi = pms[i];
  float acc[8] = {0.f,0.f,0.f,0.f,0.f,0.f,0.f,0.f};
  const float step = 8.2f/31.f;
  float rbase = 0.8f + (w*8)*step;
  for (int j=0;j<64;j++){
    if (j==i) continue;
    float d = dr[j*64+i];
    float wq = 0.f;
    if (d < 10.f) wq = 0.25f*(0.5f*cosf(0.31415926535f*d)+0.5f)*qs[j]*pms[j]*pmi;
    if (wq != 0.f){
      #pragma unroll
      for (int r=0;r<8;r++){
        float dd = d - (rbase + r*step);
        acc[r] += wq*expf(-4.f*dd*dd);
      }
    }
  }
  float* xr = extra + (size_t)(m*64+i)*XW + w*8;
  #pragma unroll
  for (int r=0;r<8;r++) xr[r] = acc[r];
}

// ---------------- screened Coulomb + energy + outputs ----------------
__global__ void final_kernel(const float* __restrict__ dbuf, const float* __restrict__ q,
                             const float* __restrict__ pmf, const float* __restrict__ ae,
                             const int* __restrict__ species, float* __restrict__ out){
  int m = blockIdx.x, a = threadIdx.x, g = m*64+a;
  __shared__ float qs[64], pms[64];
  qs[a]=q[g]; pms[a]=pmf[g];
  __syncthreads();
  float acc=0.f;
  const float* dr = dbuf + (size_t)m*4096;
  for (int b=0;b<64;b++){
    if (b==a) continue;
    float d = dr[b*64+a];
    float sgm = 1.f/(1.f+expf(-(d-2.2f)*8.5f));
    acc += qs[b]*pms[b]*sgm/d;
  }
  float e = 0.5f*qs[a]*pms[a]*acc;          // triu(k=1) sum of symmetric matrix
  float aea = pms[a]>0.f ? ae[g] : 0.f;
  float tot = wsum(e + aea);
  if (a == 0) out[NFLAT + m] = tot;
  out[g] = (float)species[g];
  out[NFLAT + NMOL + g] = qs[a];
}

extern "C" void kernel_launch(void* const* d_in, const int* in_sizes, int n_in,
                              void* d_out, int out_size, void* d_ws, size_t ws_size,
                              hipStream_t stream){
  const int*   species = (const int*)d_in[0];
  const float* coord   = (const float*)d_in[1];
  const float* netq    = (const float*)d_in[2];
  const float* aev     = (const float*)d_in[3];
  const float* cW[4] = {(const float*)d_in[4],(const float*)d_in[6],(const float*)d_in[8],(const float*)d_in[10]};
  const float* cB[4] = {(const float*)d_in[5],(const float*)d_in[7],(const float*)d_in[9],(const float*)d_in[11]};
  const float* aW[4] = {(const float*)d_in[12],(const float*)d_in[14],(const float*)d_in[16],(const float*)d_in[18]};
  const float* aB[4] = {(const float*)d_in[13],(const float*)d_in[15],(const float*)d_in[17],(const float*)d_in[19]};

  // workspace layout (floats)
  float* f = (float*)d_ws;
  size_t o = 0;
  float* dbuf  = f + o; o += (size_t)NMOL*4096;
  float* sig   = f + o; o += NFLAT;
  float* invj  = f + o; o += NFLAT;
  float* pmf   = f + o; o += NFLAT;
  float* q     = f + o; o += NFLAT;
  float* chi   = f + o; o += NFLAT;
  float* extra = f + o; o += (size_t)NFLAT*XW + 64;
  float* h0    = f + o; o += (size_t)MPAD*D0;
  float* h1    = f + o; o += (size_t)MPAD*D1;
  float* h2    = h0;   // L2 reads h1 only -> alias h0
  int* meta    = (int*)(f + o); o += 64;
  int* idxarr  = (int*)(f + o); o += MPAD;
  int* blkhist = (int*)(f + o); o += NMOL*4;
  int* blkoff  = (int*)(f + o); o += NMOL*4;

  prep_kernel<<<dim3(NMOL), 256, 0, stream>>>(species, coord, dbuf, sig, invj, pmf, blkhist, extra);
  plan_kernel<<<dim3(1), 64, 0, stream>>>(blkhist, meta, blkoff);
  scatter_kernel<<<dim3(NMOL), 64, 0, stream>>>(species, blkoff, idxarr);

  for (int pass=0; pass<3; ++pass){
    const float* const* Wp = (pass<2) ? cW : aW;
    const float* const* Bp = (pass<2) ? cB : aB;
    if (pass == 0)
      gemm_mfma<2><<<dim3(516,4), 256, 0, stream>>>(nullptr, aev, extra, idxarr, meta,
                                                    Wp[0], Bp[0], h0, 418, D0, 1);
    else
      gemm_mfma<1><<<dim3(516,4), 256, 0, stream>>>(nullptr, aev, extra, idxarr, meta,
                                                    Wp[0], Bp[0], h0, 418, D0, 1);
    gemm_mfma<0><<<dim3(516,3), 256, 0, stream>>>(h0, aev, extra, idxarr, meta,
                                                  Wp[1], Bp[1], h1, D0, D1, 1);
    gemm_mfma<0><<<dim3(516,3), 256, 0, stream>>>(h1, aev, extra, idxarr, meta,
                                                  Wp[2], Bp[2], h2, D1, D2, 1);
    layer3_kernel<<<dim3(MPAD/4), 256, 0, stream>>>(h2, idxarr, meta, Wp[3], Bp[3], chi);
    if (pass < 2)
      iter_kernel<<<dim3(NMOL), 256, 0, stream>>>(chi, invj, pmf, netq, dbuf, sig, q, extra);
  }
  final_kernel<<<dim3(NMOL), 64, 0, stream>>>(dbuf, q, pmf, chi, species, (float*)d_out);
}